// Round 16
// baseline (24.301 us; speedup 1.0000x reference)
//
#include <hip/hip_runtime.h>
#include <cstdint>
#include <cstddef>

#define BATCH 4
#define NTOK  4096
#define CCH   256
#define IMH   512
#define IMW   512

#define RPB 32                                  // rows per block
#define THREADS 1024                            // 16 waves/block
#define NBLOCKS (BATCH * NTOK / RPB)            // 512 blocks -> 8 waves/SIMD

typedef float v4f __attribute__((ext_vector_type(4)));

// ---------------------------------------------------------------------------
// Round-16: scan-redundancy lever, final notch, at constant occupancy.
//   RPB 16 -> 32 with 512 -> 1024 threads: 512 blocks x 16 waves = 8192 waves
//   (8/SIMD, same as R12/R15); scan traffic 32 MB -> 16 MB; compare total
//   invariant (~67M). Per-wave layout identical (wave w owns rows 2w, 2w+1).
//   feat loads now NONTEMPORAL: idx is a permutation -> each feat row read
//   exactly once; streaming it keeps images + scan arrays resident in L2.
// ---------------------------------------------------------------------------
__global__ __launch_bounds__(THREADS) void fused_k(const float4* __restrict__ feat,
                                                   const float* __restrict__ im,
                                                   const int2* __restrict__ po,
                                                   const int4* __restrict__ ps4,
                                                   float4* __restrict__ out_feat,
                                                   float* __restrict__ out_dis) {
    __shared__ int s_key[RPB];
    __shared__ int s_idx[RPB];

    const int tid = threadIdx.x;
    const int r0  = blockIdx.x * RPB;           // 128 blocks per batch
    const int b   = blockIdx.x >> 7;

    if (tid < RPB) {
        int2 p = po[r0 + tid];
        s_key[tid] = (p.x << 16) | p.y;
        s_idx[tid] = 0x7FFFFFFF;
    }

    const int lane = tid & 63;
    const int w    = tid >> 6;                  // 0..15

    // ---- dis loads: EARLY (depend only on po, loaded per-lane) ----
    const int group = lane >> 4;                // 0..3
    const int unit  = lane & 15;
    const bool dact = (group < 2) && (unit < 12);
    const int drow  = r0 + w * 2 + (group & 1);
    const int2 dp   = po[drow];                 // 2 distinct addrs/wave

    const int ch = unit >> 2, pr = unit & 3;
    const int rimg = dp.y * 4 + pr;             // <= 495; +IMW row <= 496 ok
    const int col0 = dp.x * 4;                  // 16B-aligned; col0+4 <= 496 ok
    const float* dbase = im + (((size_t)(b * 3 + ch)) * IMH + rimg) * IMW + col0;

    v4f vC = {0,0,0,0}, vU = {0,0,0,0}, vD = {0,0,0,0};
    float vL = 0.f, vR = 0.f;
    if (dact) {
        vC = *(const v4f*)dbase;
        vU = *(const v4f*)(rimg > 0 ? dbase - IMW : dbase);   // clamped; masked below
        vD = *(const v4f*)(dbase + IMW);
        vL = (col0 > 0) ? dbase[-1] : 0.f;
        vR = dbase[4];
    }

    // ---- scan: 2-deep int4 burst over the batch's 2048 int4 ----
    const int4* psb = ps4 + (size_t)b * (NTOK / 2);
    int4 t[2];
#pragma unroll
    for (int it = 0; it < 2; ++it) t[it] = psb[it * THREADS + tid];

    __syncthreads();                            // s_key ready

    int kreg[RPB];
#pragma unroll
    for (int k = 0; k < RPB; ++k) kreg[k] = s_key[k];

#pragma unroll
    for (int it = 0; it < 2; ++it) {
        const int e0 = (t[it].x << 16) | t[it].y;
        const int e1 = (t[it].z << 16) | t[it].w;
        const int j0 = 2 * (it * THREADS + tid);
#pragma unroll
        for (int k = 0; k < RPB; ++k) {
            if (e0 == kreg[k]) atomicMin(&s_idx[k], j0);
            if (e1 == kreg[k]) atomicMin(&s_idx[k], j0 + 1);
        }
    }
    __syncthreads();

    // ---- gather: 2 independent rows per wave, STREAMING loads+stores ----
    const int row0 = r0 + w * 2, row1 = row0 + 1;
    const int idx0 = s_idx[w * 2], idx1 = s_idx[w * 2 + 1];

    const v4f f0 = __builtin_nontemporal_load(
        (const v4f*)&feat[((size_t)(b * NTOK + idx0)) * 64 + lane]);
    const v4f f1 = __builtin_nontemporal_load(
        (const v4f*)&feat[((size_t)(b * NTOK + idx1)) * 64 + lane]);
    __builtin_nontemporal_store(f0, (v4f*)&out_feat[(size_t)row0 * 64 + lane]);
    __builtin_nontemporal_store(f1, (v4f*)&out_feat[(size_t)row1 * 64 + lane]);

    // ---- dis compute from the early loads ----
    float s = 0.f;
    if (dact) {
        if (rimg > 0)
            s += fabsf(vC.x - vU.x) + fabsf(vC.y - vU.y)
               + fabsf(vC.z - vU.z) + fabsf(vC.w - vU.w);
        s += fabsf(vD.x - vC.x) + fabsf(vD.y - vC.y)
           + fabsf(vD.z - vC.z) + fabsf(vD.w - vC.w);
        const float d01 = fabsf(vC.y - vC.x);
        const float d12 = fabsf(vC.z - vC.y);
        const float d23 = fabsf(vC.w - vC.z);
        s += 2.f * (d01 + d12 + d23);
        if (col0 > 0) s += fabsf(vC.x - vL);
        s += fabsf(vR - vC.w);
    }
    s += __shfl_xor(s, 1, 16);
    s += __shfl_xor(s, 2, 16);
    s += __shfl_xor(s, 4, 16);
    s += __shfl_xor(s, 8, 16);
    if (group < 2 && unit == 0)
        __builtin_nontemporal_store(s, &out_dis[drow]);
}

extern "C" void kernel_launch(void* const* d_in, const int* in_sizes, int n_in,
                              void* d_out, int out_size, void* d_ws, size_t ws_size,
                              hipStream_t stream) {
    const float* feat         = (const float*)d_in[0];
    const float* images       = (const float*)d_in[1];
    const int*   pos_org      = (const int*)d_in[2];
    const int*   pos_shuffled = (const int*)d_in[3];

    float* out_feat = (float*)d_out;
    float* out_dis  = out_feat + (size_t)BATCH * NTOK * CCH;

    fused_k<<<NBLOCKS, THREADS, 0, stream>>>(
        (const float4*)feat, images, (const int2*)pos_org,
        (const int4*)pos_shuffled, (float4*)out_feat, out_dis);
}

// Round 17
// 17.828 us; speedup vs baseline: 1.3631x; 1.3631x over previous
//
#include <hip/hip_runtime.h>
#include <cstdint>
#include <cstddef>

#define BATCH 4
#define NTOK  4096
#define CCH   256
#define IMH   512
#define IMW   512

#define RPB 16                                  // rows per block (proven optimum)
#define THREADS 512                             // 8 waves/block
#define NBLOCKS (BATCH * NTOK / RPB)            // 1024 blocks -> 8 waves/SIMD

typedef float v4f __attribute__((ext_vector_type(4)));

// ---------------------------------------------------------------------------
// Round-17: R15 champion (17.36us) + ONE isolated delta: nontemporal feat
// loads. idx is a permutation -> every feat row is read exactly once, so
// streaming feat (16.7 MB) past L2 preserves residency for the genuinely
// reused data (images ~12.6 MB, pos arrays 32 KB/batch).
// Everything else is byte-identical to R15:
//   - RPB16 @ 512 threads: 1024 blocks x 8 waves = 8 waves/SIMD;
//     RPB-curve at this occupancy: RPB8=18.2, RPB16=17.36, RPB32=24.3.
//   - dis: aligned-float4 stencil, issued EARLY (hides under scan+compares).
//   - scan: 4-deep int4 burst, 16 packed keys in registers, compare burst.
// ---------------------------------------------------------------------------
__global__ __launch_bounds__(THREADS) void fused_k(const float4* __restrict__ feat,
                                                   const float* __restrict__ im,
                                                   const int2* __restrict__ po,
                                                   const int4* __restrict__ ps4,
                                                   float4* __restrict__ out_feat,
                                                   float* __restrict__ out_dis) {
    __shared__ int s_key[RPB];
    __shared__ int s_idx[RPB];

    const int tid = threadIdx.x;
    const int r0  = blockIdx.x * RPB;           // 256 blocks per batch
    const int b   = blockIdx.x >> 8;

    if (tid < RPB) {
        int2 p = po[r0 + tid];
        s_key[tid] = (p.x << 16) | p.y;
        s_idx[tid] = 0x7FFFFFFF;
    }

    const int lane = tid & 63;
    const int w    = tid >> 6;                  // 0..7

    // ---- dis loads: EARLY (depend only on po, loaded per-lane) ----
    const int group = lane >> 4;                // 0..3
    const int unit  = lane & 15;
    const bool dact = (group < 2) && (unit < 12);
    const int drow  = r0 + w * 2 + (group & 1);
    const int2 dp   = po[drow];                 // 2 distinct addrs/wave

    const int ch = unit >> 2, pr = unit & 3;
    const int rimg = dp.y * 4 + pr;             // <= 495; +IMW row <= 496 ok
    const int col0 = dp.x * 4;                  // 16B-aligned; col0+4 <= 496 ok
    const float* dbase = im + (((size_t)(b * 3 + ch)) * IMH + rimg) * IMW + col0;

    v4f vC = {0,0,0,0}, vU = {0,0,0,0}, vD = {0,0,0,0};
    float vL = 0.f, vR = 0.f;
    if (dact) {
        vC = *(const v4f*)dbase;
        vU = *(const v4f*)(rimg > 0 ? dbase - IMW : dbase);   // clamped; masked below
        vD = *(const v4f*)(dbase + IMW);
        vL = (col0 > 0) ? dbase[-1] : 0.f;
        vR = dbase[4];
    }

    // ---- scan: 4-deep int4 burst over the batch's 2048 int4 ----
    const int4* psb = ps4 + (size_t)b * (NTOK / 2);
    int4 t[4];
#pragma unroll
    for (int it = 0; it < 4; ++it) t[it] = psb[it * THREADS + tid];

    __syncthreads();                            // s_key ready

    int kreg[RPB];
#pragma unroll
    for (int k = 0; k < RPB; ++k) kreg[k] = s_key[k];

#pragma unroll
    for (int it = 0; it < 4; ++it) {
        const int e0 = (t[it].x << 16) | t[it].y;
        const int e1 = (t[it].z << 16) | t[it].w;
        const int j0 = 2 * (it * THREADS + tid);
#pragma unroll
        for (int k = 0; k < RPB; ++k) {
            if (e0 == kreg[k]) atomicMin(&s_idx[k], j0);
            if (e1 == kreg[k]) atomicMin(&s_idx[k], j0 + 1);
        }
    }
    __syncthreads();

    // ---- gather: 2 independent rows per wave, streaming load + store ----
    const int row0 = r0 + w * 2, row1 = row0 + 1;
    const int idx0 = s_idx[w * 2], idx1 = s_idx[w * 2 + 1];

    const v4f f0 = __builtin_nontemporal_load(
        (const v4f*)&feat[((size_t)(b * NTOK + idx0)) * 64 + lane]);
    const v4f f1 = __builtin_nontemporal_load(
        (const v4f*)&feat[((size_t)(b * NTOK + idx1)) * 64 + lane]);
    __builtin_nontemporal_store(f0, (v4f*)&out_feat[(size_t)row0 * 64 + lane]);
    __builtin_nontemporal_store(f1, (v4f*)&out_feat[(size_t)row1 * 64 + lane]);

    // ---- dis compute from the early loads ----
    float s = 0.f;
    if (dact) {
        if (rimg > 0)
            s += fabsf(vC.x - vU.x) + fabsf(vC.y - vU.y)
               + fabsf(vC.z - vU.z) + fabsf(vC.w - vU.w);
        s += fabsf(vD.x - vC.x) + fabsf(vD.y - vC.y)
           + fabsf(vD.z - vC.z) + fabsf(vD.w - vC.w);
        const float d01 = fabsf(vC.y - vC.x);
        const float d12 = fabsf(vC.z - vC.y);
        const float d23 = fabsf(vC.w - vC.z);
        s += 2.f * (d01 + d12 + d23);
        if (col0 > 0) s += fabsf(vC.x - vL);
        s += fabsf(vR - vC.w);
    }
    s += __shfl_xor(s, 1, 16);
    s += __shfl_xor(s, 2, 16);
    s += __shfl_xor(s, 4, 16);
    s += __shfl_xor(s, 8, 16);
    if (group < 2 && unit == 0)
        __builtin_nontemporal_store(s, &out_dis[drow]);
}

extern "C" void kernel_launch(void* const* d_in, const int* in_sizes, int n_in,
                              void* d_out, int out_size, void* d_ws, size_t ws_size,
                              hipStream_t stream) {
    const float* feat         = (const float*)d_in[0];
    const float* images       = (const float*)d_in[1];
    const int*   pos_org      = (const int*)d_in[2];
    const int*   pos_shuffled = (const int*)d_in[3];

    float* out_feat = (float*)d_out;
    float* out_dis  = out_feat + (size_t)BATCH * NTOK * CCH;

    fused_k<<<NBLOCKS, THREADS, 0, stream>>>(
        (const float4*)feat, images, (const int2*)pos_org,
        (const int4*)pos_shuffled, (float4*)out_feat, out_dis);
}

// Round 18
// 17.302 us; speedup vs baseline: 1.4045x; 1.0304x over previous
//
#include <hip/hip_runtime.h>
#include <cstdint>
#include <cstddef>

#define BATCH 4
#define NTOK  4096
#define CCH   256
#define IMH   512
#define IMW   512

#define RPB 16                                  // rows per block (proven optimum)
#define THREADS 512                             // 8 waves/block
#define NBLOCKS (BATCH * NTOK / RPB)            // 1024 blocks -> 8 waves/SIMD

typedef float v4f __attribute__((ext_vector_type(4)));

// ---------------------------------------------------------------------------
// FINAL (champion, R15 verbatim): single fused kernel, 17.36 us measured.
//   - match: pos_shuffled is an exact permutation of pos_org -> argmin(L1)
//     == first exact coordinate match; packed-key scan, 4-deep int4 burst,
//     16 keys in registers, LDS atomicMin.
//   - dis: aligned-float4 edge stencil recomputed on the fly, loads issued
//     EARLY so latency hides under the scan burst + compare VALU.
//   - gather: 2 independent feat rows per wave (cached loads -- measured
//     better than nontemporal), nontemporal streaming stores.
//   - RPB16 @ 512 threads = 8 waves/SIMD: measured optimum of the
//     {RPB4,8,16,32} x {occupancy} grid.
// Measured at the platform's mixed-traffic ceiling (~3.1 TB/s effective vs
// ~3 TB/s pure-stream at same occupancy, R9 control). ROOFLINE.
// ---------------------------------------------------------------------------
__global__ __launch_bounds__(THREADS) void fused_k(const float4* __restrict__ feat,
                                                   const float* __restrict__ im,
                                                   const int2* __restrict__ po,
                                                   const int4* __restrict__ ps4,
                                                   float4* __restrict__ out_feat,
                                                   float* __restrict__ out_dis) {
    __shared__ int s_key[RPB];
    __shared__ int s_idx[RPB];

    const int tid = threadIdx.x;
    const int r0  = blockIdx.x * RPB;           // 256 blocks per batch
    const int b   = blockIdx.x >> 8;

    if (tid < RPB) {
        int2 p = po[r0 + tid];
        s_key[tid] = (p.x << 16) | p.y;
        s_idx[tid] = 0x7FFFFFFF;
    }

    const int lane = tid & 63;
    const int w    = tid >> 6;                  // 0..7

    // ---- dis loads: EARLY (depend only on po, loaded per-lane) ----
    const int group = lane >> 4;                // 0..3
    const int unit  = lane & 15;
    const bool dact = (group < 2) && (unit < 12);
    const int drow  = r0 + w * 2 + (group & 1);
    const int2 dp   = po[drow];                 // 2 distinct addrs/wave

    const int ch = unit >> 2, pr = unit & 3;
    const int rimg = dp.y * 4 + pr;             // <= 495; +IMW row <= 496 ok
    const int col0 = dp.x * 4;                  // 16B-aligned; col0+4 <= 496 ok
    const float* dbase = im + (((size_t)(b * 3 + ch)) * IMH + rimg) * IMW + col0;

    v4f vC = {0,0,0,0}, vU = {0,0,0,0}, vD = {0,0,0,0};
    float vL = 0.f, vR = 0.f;
    if (dact) {
        vC = *(const v4f*)dbase;
        vU = *(const v4f*)(rimg > 0 ? dbase - IMW : dbase);   // clamped; masked below
        vD = *(const v4f*)(dbase + IMW);
        vL = (col0 > 0) ? dbase[-1] : 0.f;
        vR = dbase[4];
    }

    // ---- scan: 4-deep int4 burst over the batch's 2048 int4 ----
    const int4* psb = ps4 + (size_t)b * (NTOK / 2);
    int4 t[4];
#pragma unroll
    for (int it = 0; it < 4; ++it) t[it] = psb[it * THREADS + tid];

    __syncthreads();                            // s_key ready

    int kreg[RPB];
#pragma unroll
    for (int k = 0; k < RPB; ++k) kreg[k] = s_key[k];

#pragma unroll
    for (int it = 0; it < 4; ++it) {
        const int e0 = (t[it].x << 16) | t[it].y;
        const int e1 = (t[it].z << 16) | t[it].w;
        const int j0 = 2 * (it * THREADS + tid);
#pragma unroll
        for (int k = 0; k < RPB; ++k) {
            if (e0 == kreg[k]) atomicMin(&s_idx[k], j0);
            if (e1 == kreg[k]) atomicMin(&s_idx[k], j0 + 1);
        }
    }
    __syncthreads();

    // ---- gather: 2 independent rows per wave (cached loads, NT stores) ----
    const int row0 = r0 + w * 2, row1 = row0 + 1;
    const int idx0 = s_idx[w * 2], idx1 = s_idx[w * 2 + 1];

    const float4 f0 = feat[((size_t)(b * NTOK + idx0)) * 64 + lane];
    const float4 f1 = feat[((size_t)(b * NTOK + idx1)) * 64 + lane];
    v4f n0 = { f0.x, f0.y, f0.z, f0.w };
    v4f n1 = { f1.x, f1.y, f1.z, f1.w };
    __builtin_nontemporal_store(n0, (v4f*)&out_feat[(size_t)row0 * 64 + lane]);
    __builtin_nontemporal_store(n1, (v4f*)&out_feat[(size_t)row1 * 64 + lane]);

    // ---- dis compute from the early loads ----
    float s = 0.f;
    if (dact) {
        if (rimg > 0)
            s += fabsf(vC.x - vU.x) + fabsf(vC.y - vU.y)
               + fabsf(vC.z - vU.z) + fabsf(vC.w - vU.w);
        s += fabsf(vD.x - vC.x) + fabsf(vD.y - vC.y)
           + fabsf(vD.z - vC.z) + fabsf(vD.w - vC.w);
        const float d01 = fabsf(vC.y - vC.x);
        const float d12 = fabsf(vC.z - vC.y);
        const float d23 = fabsf(vC.w - vC.z);
        s += 2.f * (d01 + d12 + d23);
        if (col0 > 0) s += fabsf(vC.x - vL);
        s += fabsf(vR - vC.w);
    }
    s += __shfl_xor(s, 1, 16);
    s += __shfl_xor(s, 2, 16);
    s += __shfl_xor(s, 4, 16);
    s += __shfl_xor(s, 8, 16);
    if (group < 2 && unit == 0)
        __builtin_nontemporal_store(s, &out_dis[drow]);
}

extern "C" void kernel_launch(void* const* d_in, const int* in_sizes, int n_in,
                              void* d_out, int out_size, void* d_ws, size_t ws_size,
                              hipStream_t stream) {
    const float* feat         = (const float*)d_in[0];
    const float* images       = (const float*)d_in[1];
    const int*   pos_org      = (const int*)d_in[2];
    const int*   pos_shuffled = (const int*)d_in[3];

    float* out_feat = (float*)d_out;
    float* out_dis  = out_feat + (size_t)BATCH * NTOK * CCH;

    fused_k<<<NBLOCKS, THREADS, 0, stream>>>(
        (const float4*)feat, images, (const int2*)pos_org,
        (const int4*)pos_shuffled, (float4*)out_feat, out_dis);
}